// Round 1
// baseline (100.469 us; speedup 1.0000x reference)
//
#include <hip/hip_runtime.h>
#include <hip/hip_bf16.h>

#define MASK_ID 50264
#define Bn 16
#define Sn 2048
#define Hn 1024
#define Ln 128

// ---------------- kernel 1: first index of MASK per batch ----------------
__global__ void maskpos_k(const int* __restrict__ ids, int* __restrict__ mp) {
    int b = blockIdx.x;
    int tid = threadIdx.x;
    int lm = Sn;
    for (int s = tid; s < Sn; s += 256)
        if (ids[(long long)b * Sn + s] == MASK_ID) lm = min(lm, s);
    for (int m = 32; m; m >>= 1) lm = min(lm, __shfl_xor(lm, m));
    __shared__ int t4[4];
    int wave = tid >> 6, lane = tid & 63;
    if (lane == 0) t4[wave] = lm;
    __syncthreads();
    if (tid == 0) {
        int r = min(min(t4[0], t4[1]), min(t4[2], t4[3]));
        mp[b] = (r == Sn) ? 0 : r;   // argmax(all-false) == 0 semantics
    }
}

// ---------------- kernel 2: x[b,:] = W * q[b,maskpos[b],:] + bias ----------------
__global__ void compute_x(const float* __restrict__ q, const int* __restrict__ mp,
                          const float* __restrict__ W, const float* __restrict__ bias,
                          float* __restrict__ x) {
    int b  = blockIdx.y;
    int ot = blockIdx.x;           // 16 tiles of 64 outputs
    __shared__ float v[Hn];
    const float* src = q + ((long long)b * Sn + mp[b]) * Hn;
    int tid = threadIdx.x;
    ((float4*)v)[tid] = ((const float4*)src)[tid];   // 256 threads * 16B = 4KB
    __syncthreads();
    int wave = tid >> 6, lane = tid & 63;
    for (int j = 0; j < 16; ++j) {
        int o = ot * 64 + wave * 16 + j;
        const float* wr = W + (long long)o * Hn;
        float acc = 0.f;
        #pragma unroll
        for (int k = 0; k < 16; ++k) acc += wr[lane + k * 64] * v[lane + k * 64];
        for (int m = 32; m; m >>= 1) acc += __shfl_xor(acc, m);
        if (lane == 0) x[b * Hn + o] = acc + bias[o];
    }
}

// ---------------- kernel 3: tiled f32 GEMM over gathered rows, fused row-reduce ----
// rows r = b*L + l ; source row = sequence_output[b, offsets[l], :]
// outputs: yn2p[row*16 + bx] , dotp[row*16 + bx]   (bx = N-tile index, 16 tiles)
#define BM 64
#define BN 64
#define BK 16
__global__ __launch_bounds__(256) void gemm_fused(
        const float* __restrict__ seq, const int* __restrict__ offsets,
        const float* __restrict__ W, const float* __restrict__ bias,
        const float* __restrict__ x,
        float* __restrict__ yn2p, float* __restrict__ dotp) {
    __shared__ float As[BK][BM];     // transposed: [k][row]
    __shared__ float Bs[BK][BN];     // transposed: [k][o]
    __shared__ float red[2][BM][16];

    const int bx = blockIdx.x;       // N tile 0..15
    const int by = blockIdx.y;       // M tile 0..31
    const int tid = threadIdx.x;
    const int tx = tid & 15;
    const int ty = tid >> 4;
    const int rbase = by * BM;
    const int cbase = bx * BN;

    // staging assignment: thread -> (tile row = tid>>2, 4 consecutive k at (tid&3)*4)
    const int arow = tid >> 2;
    const int ak   = (tid & 3) * 4;
    const int grow = rbase + arow;          // global gathered row
    const int gb   = grow >> 7;             // batch
    const int gl   = grow & 127;            // l
    const float* aptr = seq + ((long long)gb * Sn + (long long)offsets[gl]) * Hn;
    const float* wptr = W + (long long)(cbase + arow) * Hn;

    float acc[4][4];
    #pragma unroll
    for (int i = 0; i < 4; ++i)
        #pragma unroll
        for (int j = 0; j < 4; ++j) acc[i][j] = 0.f;

    for (int k = 0; k < Hn; k += BK) {
        float4 av = *(const float4*)(aptr + k + ak);
        As[ak + 0][arow] = av.x; As[ak + 1][arow] = av.y;
        As[ak + 2][arow] = av.z; As[ak + 3][arow] = av.w;
        float4 wv = *(const float4*)(wptr + k + ak);
        Bs[ak + 0][arow] = wv.x; Bs[ak + 1][arow] = wv.y;
        Bs[ak + 2][arow] = wv.z; Bs[ak + 3][arow] = wv.w;
        __syncthreads();
        #pragma unroll
        for (int kk = 0; kk < BK; ++kk) {
            float4 a4 = *(const float4*)&As[kk][ty * 4];
            float4 b4 = *(const float4*)&Bs[kk][tx * 4];
            float a[4] = {a4.x, a4.y, a4.z, a4.w};
            float bb[4] = {b4.x, b4.y, b4.z, b4.w};
            #pragma unroll
            for (int i = 0; i < 4; ++i)
                #pragma unroll
                for (int j = 0; j < 4; ++j) acc[i][j] += a[i] * bb[j];
        }
        __syncthreads();
    }

    // fused epilogue: per-row partial ||y||^2 and x.y over this block's 64 o's
    #pragma unroll
    for (int i = 0; i < 4; ++i) {
        int lrow = ty * 4 + i;
        int row  = rbase + lrow;
        int bb   = row >> 7;
        float yn2 = 0.f, dt = 0.f;
        #pragma unroll
        for (int j = 0; j < 4; ++j) {
            int o = cbase + tx * 4 + j;
            float y = acc[i][j] + bias[o];
            yn2 += y * y;
            dt  += x[bb * Hn + o] * y;
        }
        red[0][lrow][tx] = yn2;
        red[1][lrow][tx] = dt;
    }
    __syncthreads();
    if (tid < BM) {
        float s0 = 0.f, s1 = 0.f;
        #pragma unroll
        for (int t = 0; t < 16; ++t) { s0 += red[0][tid][t]; s1 += red[1][tid][t]; }
        int row = rbase + tid;
        yn2p[row * 16 + bx] = s0;
        dotp[row * 16 + bx] = s1;
    }
}

// ---------------- kernel 4: per-batch loss ----------------
__global__ void finalize_k(const float* __restrict__ x,
                           const float* __restrict__ yn2p, const float* __restrict__ dotp,
                           const int* __restrict__ labels, const int* __restrict__ events,
                           float* __restrict__ lossb) {
    int b = blockIdx.x;
    int tid = threadIdx.x;
    int wave = tid >> 6, lane = tid & 63;
    // ||x[b]||^2
    float s = 0.f;
    for (int o = tid; o < Hn; o += 256) { float vv = x[b * Hn + o]; s += vv * vv; }
    for (int m = 32; m; m >>= 1) s += __shfl_xor(s, m);
    __shared__ float t4[4];
    if (lane == 0) t4[wave] = s;
    __syncthreads();
    float xn = sqrtf(t4[0] + t4[1] + t4[2] + t4[3]);

    float numt = 0.f, dent = 0.f;
    if (tid < Ln) {
        int row = b * Ln + tid;
        float yn2 = 0.f, dt = 0.f;
        #pragma unroll
        for (int i = 0; i < 16; ++i) { yn2 += yn2p[row * 16 + i]; dt += dotp[row * 16 + i]; }
        float yn = sqrtf(yn2);
        float c = dt / fmaxf(xn * yn, 1e-8f);
        float e = expf(c);
        numt = e * (float)labels[row];
        dent = e * (float)events[row];
    }
    for (int m = 32; m; m >>= 1) { numt += __shfl_xor(numt, m); dent += __shfl_xor(dent, m); }
    __shared__ float tn[4], td[4];
    if (lane == 0) { tn[wave] = numt; td[wave] = dent; }
    __syncthreads();
    if (tid == 0) {
        float num = tn[0] + tn[1] + tn[2] + tn[3];
        float den = td[0] + td[1] + td[2] + td[3];
        lossb[b] = logf(den) - logf(num);   // -log(num/den)
    }
}

// ---------------- kernel 5: mean ----------------
__global__ void mean_k(const float* __restrict__ lossb, float* __restrict__ out) {
    int tid = threadIdx.x;
    float v = (tid < Bn) ? lossb[tid] : 0.f;
    for (int m = 32; m; m >>= 1) v += __shfl_xor(v, m);
    if (tid == 0) out[0] = v * (1.0f / Bn);
}

extern "C" void kernel_launch(void* const* d_in, const int* in_sizes, int n_in,
                              void* d_out, int out_size, void* d_ws, size_t ws_size,
                              hipStream_t stream) {
    const int*   input_ids = (const int*)d_in[0];
    const float* q         = (const float*)d_in[1];
    const float* seq       = (const float*)d_in[2];
    const int*   events    = (const int*)d_in[3];
    const int*   labels    = (const int*)d_in[4];
    const int*   offsets   = (const int*)d_in[5];
    // d_in[6] = lengths (unused by reference math)
    const float* W         = (const float*)d_in[7];
    const float* bias      = (const float*)d_in[8];
    float* out = (float*)d_out;

    char* ws = (char*)d_ws;
    int*   mp    = (int*)ws;                                   // 16 ints
    float* x     = (float*)(ws + 4096);                        // 16*1024 f32
    float* yn2p  = (float*)(ws + 4096 + 65536);                // 2048*16 f32
    float* dotp  = (float*)(ws + 4096 + 65536 + 131072);       // 2048*16 f32
    float* lossb = (float*)(ws + 4096 + 65536 + 262144);       // 16 f32

    maskpos_k<<<Bn, 256, 0, stream>>>(input_ids, mp);
    compute_x<<<dim3(16, Bn), 256, 0, stream>>>(q, mp, W, bias, x);
    gemm_fused<<<dim3(16, 32), 256, 0, stream>>>(seq, offsets, W, bias, x, yn2p, dotp);
    finalize_k<<<Bn, 256, 0, stream>>>(x, yn2p, dotp, labels, events, lossb);
    mean_k<<<1, 64, 0, stream>>>(lossb, out);
}

// Round 2
// 65.899 us; speedup vs baseline: 1.5246x; 1.5246x over previous
//
#include <hip/hip_runtime.h>
#include <hip/hip_bf16.h>

#define MASK_ID 50264
#define Bn 16
#define Sn 2048
#define Hn 1024
#define Ln 128

typedef __attribute__((ext_vector_type(8))) short short8;
typedef __attribute__((ext_vector_type(4))) float f32x4;

__device__ __forceinline__ unsigned short f2bf(float f) {
    __hip_bfloat16 h = __float2bfloat16(f);
    return __builtin_bit_cast(unsigned short, h);
}
__device__ __forceinline__ void gload16(const void* g, void* l) {
    __builtin_amdgcn_global_load_lds((const __attribute__((address_space(1))) void*)g,
                                     (__attribute__((address_space(3))) void*)l, 16, 0, 0);
}

// ---------------- kernel 1: first index of MASK per batch ----------------
__global__ void maskpos_k(const int* __restrict__ ids, int* __restrict__ mp) {
    int b = blockIdx.x;
    int tid = threadIdx.x;
    int lm = Sn;
    for (int s = tid; s < Sn; s += 256)
        if (ids[(long long)b * Sn + s] == MASK_ID) lm = min(lm, s);
    for (int m = 32; m; m >>= 1) lm = min(lm, __shfl_xor(lm, m));
    __shared__ int t4[4];
    int wave = tid >> 6, lane = tid & 63;
    if (lane == 0) t4[wave] = lm;
    __syncthreads();
    if (tid == 0) {
        int r = min(min(t4[0], t4[1]), min(t4[2], t4[3]));
        mp[b] = (r == Sn) ? 0 : r;
    }
}

// ---------------- kernel 2: gather rows -> bf16, convert W -> bf16 ----------------
// blocks 0..2047: Apack[row] = bf16(seq[b, offsets[l], :]),  row = b*128+l
// blocks 2048..3071: Wb[r] = bf16(W[r, :])
__global__ void prep_k(const float* __restrict__ seq, const int* __restrict__ offsets,
                       const float* __restrict__ W,
                       unsigned short* __restrict__ Apack, unsigned short* __restrict__ Wb) {
    int blk = blockIdx.x, tid = threadIdx.x;
    const float* src;
    unsigned short* dst;
    if (blk < 2048) {
        int b = blk >> 7, l = blk & 127;
        src = seq + ((long long)b * Sn + (long long)offsets[l]) * Hn;
        dst = Apack + (long long)blk * Hn;
    } else {
        int r = blk - 2048;
        src = W + (long long)r * Hn;
        dst = Wb + (long long)r * Hn;
    }
    float4 v = ((const float4*)src)[tid];
    ushort4 u = make_ushort4(f2bf(v.x), f2bf(v.y), f2bf(v.z), f2bf(v.w));
    ((ushort4*)dst)[tid] = u;
}

// ---------------- kernel 3: x[b,:] = W * q[b,maskpos[b],:] + bias (reads W once) ----
__global__ __launch_bounds__(256) void compute_x2(
        const float* __restrict__ q, const int* __restrict__ mp,
        const float* __restrict__ W, const float* __restrict__ bias,
        float* __restrict__ x) {
    __shared__ float qs[Bn][Hn];     // 64 KB
    int tid = threadIdx.x;
    for (int b = 0; b < Bn; ++b) {
        const float* src = q + ((long long)b * Sn + mp[b]) * Hn;
        ((float4*)qs[b])[tid] = ((const float4*)src)[tid];
    }
    __syncthreads();
    int wv = tid >> 6, l = tid & 63;
    int obase = blockIdx.x * 16;
    for (int j = 0; j < 4; ++j) {
        int o = obase + wv * 4 + j;
        float wr[16];
        #pragma unroll
        for (int t = 0; t < 16; ++t) wr[t] = W[(long long)o * Hn + t * 64 + l];
        for (int b = 0; b < Bn; ++b) {
            float acc = 0.f;
            #pragma unroll
            for (int t = 0; t < 16; ++t) acc += wr[t] * qs[b][t * 64 + l];
            for (int m = 32; m; m >>= 1) acc += __shfl_xor(acc, m);
            if (l == 0) x[b * Hn + o] = acc + bias[o];
        }
    }
}

// ---------------- kernel 4: bf16 MFMA GEMM (128x64 tile) + fused row reductions ----
// grid 256 blocks (16 M x 16 N, XCD-swizzled), 256 threads (4 waves, 2x2 wave grid)
// wave tile 64x32, mfma_f32_16x16x32_bf16. LDS chunk-XOR swizzle, gload_lds staging,
// double-buffered 2-phase prefetch.
__global__ __launch_bounds__(256) void gemm_bf16(
        const unsigned short* __restrict__ Apack, const unsigned short* __restrict__ Wb,
        const float* __restrict__ bias, const float* __restrict__ x,
        float* __restrict__ yn2p, float* __restrict__ dotp) {
    __shared__ unsigned short As[2][128 * 32];   // 2 x 8 KB, [row][64B], chunk-XOR
    __shared__ unsigned short Bs[2][64 * 32];    // 2 x 4 KB
    __shared__ float red[2][128][2];

    const int wg = blockIdx.x;
    const int swz = (wg & 7) * 32 + (wg >> 3);   // XCD-contiguous M-panels
    const int by = swz >> 4;                     // M tile 0..15 (= batch)
    const int bx = swz & 15;                     // N tile 0..15
    const int tid = threadIdx.x;
    const int wv = tid >> 6, l = tid & 63;
    const int wm = wv >> 1, wn = wv & 1;
    const int rbase = by * 128, cbase = bx * 64;

    // staging: thread -> (LDS row sr = tid>>2, physical 16B chunk sc = tid&3)
    const int sr = tid >> 2, sc = tid & 3;
    const unsigned short* aSrc0 = Apack + (long long)(rbase + sr) * Hn + (sc ^ (sr & 3)) * 8;
    const unsigned short* aSrc1 = aSrc0 + 64 * Hn;
    const unsigned short* bSrc  = Wb + (long long)(cbase + sr) * Hn + (sc ^ (sr & 3)) * 8;
    char* AsB = (char*)As;
    char* BsB = (char*)Bs;
    char* aDst0 = AsB + wv * 1024;
    char* aDst1 = AsB + 4096 + wv * 1024;
    char* bDst  = BsB + wv * 1024;

    // fragment read offsets (bytes): row = wm*64 + mf*16 + (l&15); phys chunk = (l>>4)^(row&3)
    const int phys = (l >> 4) ^ (l & 3);
    const int abase = (wm * 64 + (l & 15)) * 64 + phys * 16;
    const int bbase = (wn * 32 + (l & 15)) * 64 + phys * 16;

    // epilogue x/bias preload
    float xv[2], bv[2];
    #pragma unroll
    for (int nf = 0; nf < 2; ++nf) {
        int o = cbase + wn * 32 + nf * 16 + (l & 15);
        xv[nf] = x[by * Hn + o];
        bv[nf] = bias[o];
    }

    f32x4 acc[4][2];
    #pragma unroll
    for (int i = 0; i < 4; ++i)
        #pragma unroll
        for (int j = 0; j < 2; ++j) acc[i][j] = (f32x4){0.f, 0.f, 0.f, 0.f};

    #define STAGE(buf, ks_) do { \
        int k0_ = (ks_) * 32; \
        gload16(aSrc0 + k0_, AsB + (buf) * 8192 + wv * 1024); \
        gload16(aSrc1 + k0_, AsB + (buf) * 8192 + 4096 + wv * 1024); \
        gload16(bSrc  + k0_, BsB + (buf) * 4096 + wv * 1024); \
    } while (0)

    STAGE(0, 0);
    __syncthreads();
    for (int ks = 0; ks < 32; ++ks) {
        int cur = ks & 1;
        if (ks + 1 < 32) STAGE(cur ^ 1, ks + 1);
        const char* Ab = AsB + cur * 8192;
        const char* Bb = BsB + cur * 4096;
        short8 af[4], bfr[2];
        #pragma unroll
        for (int mf = 0; mf < 4; ++mf) af[mf] = *(const short8*)(Ab + abase + mf * 1024);
        #pragma unroll
        for (int nf = 0; nf < 2; ++nf) bfr[nf] = *(const short8*)(Bb + bbase + nf * 1024);
        #pragma unroll
        for (int mf = 0; mf < 4; ++mf)
            #pragma unroll
            for (int nf = 0; nf < 2; ++nf)
                acc[mf][nf] = __builtin_amdgcn_mfma_f32_16x16x32_bf16(af[mf], bfr[nf], acc[mf][nf], 0, 0, 0);
        __syncthreads();
    }
    #undef STAGE

    // epilogue: per-row ||y||^2 and x.y partials over this block's 64 cols
    #pragma unroll
    for (int mf = 0; mf < 4; ++mf) {
        #pragma unroll
        for (int reg = 0; reg < 4; ++reg) {
            float y2 = 0.f, xy = 0.f;
            #pragma unroll
            for (int nf = 0; nf < 2; ++nf) {
                float y = acc[mf][nf][reg] + bv[nf];
                y2 += y * y;
                xy += xv[nf] * y;
            }
            #pragma unroll
            for (int m = 8; m; m >>= 1) {
                y2 += __shfl_xor(y2, m);
                xy += __shfl_xor(xy, m);
            }
            if ((l & 15) == 0) {
                int rl = wm * 64 + mf * 16 + (l >> 4) * 4 + reg;
                red[wn][rl][0] = y2;
                red[wn][rl][1] = xy;
            }
        }
    }
    __syncthreads();
    {
        int row = tid >> 1, v = tid & 1;
        float s = red[0][row][v] + red[1][row][v];
        float* out = v ? dotp : yn2p;
        out[(rbase + row) * 16 + bx] = s;
    }
}

// ---------------- kernel 5: per-batch loss ----------------
__global__ void finalize_k(const float* __restrict__ x,
                           const float* __restrict__ yn2p, const float* __restrict__ dotp,
                           const int* __restrict__ labels, const int* __restrict__ events,
                           float* __restrict__ lossb) {
    int b = blockIdx.x;
    int tid = threadIdx.x;
    int wave = tid >> 6, lane = tid & 63;
    float s = 0.f;
    for (int o = tid; o < Hn; o += 256) { float vv = x[b * Hn + o]; s += vv * vv; }
    for (int m = 32; m; m >>= 1) s += __shfl_xor(s, m);
    __shared__ float t4[4];
    if (lane == 0) t4[wave] = s;
    __syncthreads();
    float xn = sqrtf(t4[0] + t4[1] + t4[2] + t4[3]);

    float numt = 0.f, dent = 0.f;
    if (tid < Ln) {
        int row = b * Ln + tid;
        float yn2 = 0.f, dt = 0.f;
        #pragma unroll
        for (int i = 0; i < 16; ++i) { yn2 += yn2p[row * 16 + i]; dt += dotp[row * 16 + i]; }
        float yn = sqrtf(yn2);
        float c = dt / fmaxf(xn * yn, 1e-8f);
        float e = expf(c);
        numt = e * (float)labels[row];
        dent = e * (float)events[row];
    }
    for (int m = 32; m; m >>= 1) { numt += __shfl_xor(numt, m); dent += __shfl_xor(dent, m); }
    __shared__ float tn[4], td[4];
    if (lane == 0) { tn[wave] = numt; td[wave] = dent; }
    __syncthreads();
    if (tid == 0) {
        float num = tn[0] + tn[1] + tn[2] + tn[3];
        float den = td[0] + td[1] + td[2] + td[3];
        lossb[b] = logf(den) - logf(num);
    }
}

// ---------------- kernel 6: mean ----------------
__global__ void mean_k(const float* __restrict__ lossb, float* __restrict__ out) {
    int tid = threadIdx.x;
    float v = (tid < Bn) ? lossb[tid] : 0.f;
    for (int m = 32; m; m >>= 1) v += __shfl_xor(v, m);
    if (tid == 0) out[0] = v * (1.0f / Bn);
}

extern "C" void kernel_launch(void* const* d_in, const int* in_sizes, int n_in,
                              void* d_out, int out_size, void* d_ws, size_t ws_size,
                              hipStream_t stream) {
    const int*   input_ids = (const int*)d_in[0];
    const float* q         = (const float*)d_in[1];
    const float* seq       = (const float*)d_in[2];
    const int*   events    = (const int*)d_in[3];
    const int*   labels    = (const int*)d_in[4];
    const int*   offsets   = (const int*)d_in[5];
    const float* W         = (const float*)d_in[7];
    const float* bias      = (const float*)d_in[8];
    float* out = (float*)d_out;

    char* ws = (char*)d_ws;
    int*            mp    = (int*)ws;                          // @0        64 B
    float*          x     = (float*)(ws + 4096);               // @4K       64 KB
    float*          yn2p  = (float*)(ws + 69632);              // @68K      128 KB
    float*          dotp  = (float*)(ws + 200704);             // @196K     128 KB
    float*          lossb = (float*)(ws + 331776);             // @324K     64 B
    unsigned short* Apack = (unsigned short*)(ws + 393216);    // @384K     4 MB
    unsigned short* Wb    = (unsigned short*)(ws + 4587520);   // @4.375M   2 MB

    maskpos_k <<<Bn, 256, 0, stream>>>(input_ids, mp);
    prep_k    <<<3072, 256, 0, stream>>>(seq, offsets, W, Apack, Wb);
    compute_x2<<<64, 256, 0, stream>>>(q, mp, W, bias, x);
    gemm_bf16 <<<256, 256, 0, stream>>>(Apack, Wb, bias, x, yn2p, dotp);
    finalize_k<<<Bn, 256, 0, stream>>>(x, yn2p, dotp, labels, events, lossb);
    mean_k    <<<1, 64, 0, stream>>>(lossb, out);
}

// Round 3
// 36.205 us; speedup vs baseline: 2.7750x; 1.8201x over previous
//
#include <hip/hip_runtime.h>
#include <hip/hip_bf16.h>

#define MASK_ID 50264
#define Bn 16
#define Sn 2048
#define Hn 1024
#define Ln 128

typedef __attribute__((ext_vector_type(8))) short short8;
typedef __attribute__((ext_vector_type(4))) float f32x4;

__device__ __forceinline__ unsigned short f2bf(float f) {
    __hip_bfloat16 h = __float2bfloat16(f);
    return __builtin_bit_cast(unsigned short, h);
}
__device__ __forceinline__ void gload16(const void* g, void* l) {
    __builtin_amdgcn_global_load_lds((const __attribute__((address_space(1))) void*)g,
                                     (__attribute__((address_space(3))) void*)l, 16, 0, 0);
}

// ============ kernel 1: prep ============
// blocks 0..383   : 8 rows each -> gather A rows (0..2047) / convert W rows (2048..3071) to bf16
// blocks 384..399 : batch b = blk-384: find mask pos, convert q[b, mp, :] to bf16
__global__ __launch_bounds__(256) void prep_k(
        const int* __restrict__ ids, const float* __restrict__ q,
        const float* __restrict__ seq, const int* __restrict__ offsets,
        const float* __restrict__ W,
        unsigned short* __restrict__ Apack, unsigned short* __restrict__ Wb,
        unsigned short* __restrict__ Qb) {
    __shared__ int t4[4];
    int blk = blockIdx.x, tid = threadIdx.x;
    if (blk < 384) {
        #pragma unroll
        for (int r8 = 0; r8 < 8; ++r8) {
            int row = blk * 8 + r8;
            const float* src;
            unsigned short* dst;
            if (row < 2048) {
                int b = row >> 7, l = row & 127;
                src = seq + ((long long)b * Sn + (long long)offsets[l]) * Hn;
                dst = Apack + (long long)row * Hn;
            } else {
                int r = row - 2048;
                src = W + (long long)r * Hn;
                dst = Wb + (long long)r * Hn;
            }
            float4 v = ((const float4*)src)[tid];
            ((ushort4*)dst)[tid] = make_ushort4(f2bf(v.x), f2bf(v.y), f2bf(v.z), f2bf(v.w));
        }
    } else {
        int b = blk - 384;
        int lm = Sn;
        for (int s = tid; s < Sn; s += 256)
            if (ids[b * Sn + s] == MASK_ID) lm = min(lm, s);
        for (int m = 32; m; m >>= 1) lm = min(lm, __shfl_xor(lm, m));
        int wv = tid >> 6, l = tid & 63;
        if (l == 0) t4[wv] = lm;
        __syncthreads();
        int mp = min(min(t4[0], t4[1]), min(t4[2], t4[3]));
        if (mp == Sn) mp = 0;
        const float* src = q + ((long long)b * Sn + mp) * Hn;
        float4 v = ((const float4*)src)[tid];
        ((ushort4*)(Qb + b * Hn))[tid] = make_ushort4(f2bf(v.x), f2bf(v.y), f2bf(v.z), f2bf(v.w));
    }
}

// ============ kernel 2: bf16 MFMA GEMM 128x32 tiles + fused x and row reductions ====
// grid 512 (16 M-tiles x 32 N-tiles, XCD-grouped by M), 256 threads (4 waves).
// Wave w computes rows [w*32, w*32+32) of the tile; waves 2,3 additionally compute
// x = W*q + b for this tile's 32 columns via one extra MFMA (A = broadcast q-row).
// Outputs: yn2p[bx][2048], dotp[bx][2048], xn2p[bx][16].
__global__ __launch_bounds__(256) void gemm_k(
        const unsigned short* __restrict__ Apack, const unsigned short* __restrict__ Wb,
        const unsigned short* __restrict__ Qb, const float* __restrict__ bias,
        float* __restrict__ yn2p, float* __restrict__ dotp, float* __restrict__ xn2p) {
    __shared__ unsigned short As[2][4096];   // [buf][ 2 x (64 rows x 64B) ] = 8KB per buf
    __shared__ unsigned short Bs[2][1024];   // [buf][ 32 cols x 64B ]       = 2KB per buf
    __shared__ unsigned short qs[1024];      // q row, linear, 2KB
    __shared__ float xvs[32];
    __shared__ float xred[2];
    __shared__ float red[128][2];

    const int wg = blockIdx.x;
    const int swz = (wg & 7) * 64 + (wg >> 3);   // bijective (512 % 8 == 0), groups by-M per XCD
    const int by = swz >> 5;                     // 0..15
    const int bx = swz & 31;                     // 0..31
    const int tid = threadIdx.x;
    const int wv = tid >> 6, l = tid & 63;
    const int rbase = by * 128, cbase = bx * 32;

    // staging sources: 4 lanes stage 64B contiguous of one row (coalesced)
    const unsigned short* aSrc0 = Apack + (long long)(rbase + (tid >> 2)) * Hn + (tid & 3) * 8;
    const unsigned short* aSrc1 = aSrc0 + 64 * Hn;
    const unsigned short* bSrc  = Wb + (long long)(cbase + (tid >> 2)) * Hn + (tid & 3) * 8;
    char* AsB = (char*)As;
    char* BsB = (char*)Bs;
    char* qsB = (char*)qs;

    // fragment read geometry: addr(row,c) = (row>>6)*4096 + (row&63)*64 + c*16
    const int rsub  = (wv & 1) * 32 + (l & 15);
    const int rhigh = (wv >> 1) * 4096;
    const int coff  = (l >> 4) * 16;
    const int csub  = (l & 15) * 64;

    float bv0 = bias[cbase + (l & 15)];
    float bv1 = bias[cbase + 16 + (l & 15)];

    f32x4 acc00 = {0,0,0,0}, acc01 = {0,0,0,0}, acc10 = {0,0,0,0}, acc11 = {0,0,0,0};
    f32x4 xacc = {0,0,0,0};

    #define STAGE(buf, ks_) do { \
        gload16(aSrc0 + (ks_) * 32, AsB + (buf) * 8192 + wv * 1024); \
        gload16(aSrc1 + (ks_) * 32, AsB + (buf) * 8192 + 4096 + wv * 1024); \
        if (wv < 2) gload16(bSrc + (ks_) * 32, BsB + (buf) * 2048 + wv * 1024); \
    } while (0)

    if (wv >= 2) gload16(Qb + by * Hn + ((wv - 2) * 64 + l) * 8, qsB + (wv - 2) * 1024);
    STAGE(0, 0);
    __syncthreads();
    for (int ks = 0; ks < 32; ++ks) {
        int cur = ks & 1;
        if (ks + 1 < 32) STAGE(cur ^ 1, ks + 1);
        const char* Ab = AsB + cur * 8192 + rhigh;
        const char* Bb = BsB + cur * 2048;
        short8 af0 = *(const short8*)(Ab + rsub * 64 + coff);
        short8 af1 = *(const short8*)(Ab + (rsub + 16) * 64 + coff);
        short8 bf0 = *(const short8*)(Bb + csub + coff);
        short8 bf1 = *(const short8*)(Bb + 1024 + csub + coff);
        acc00 = __builtin_amdgcn_mfma_f32_16x16x32_bf16(af0, bf0, acc00, 0, 0, 0);
        acc01 = __builtin_amdgcn_mfma_f32_16x16x32_bf16(af0, bf1, acc01, 0, 0, 0);
        acc10 = __builtin_amdgcn_mfma_f32_16x16x32_bf16(af1, bf0, acc10, 0, 0, 0);
        acc11 = __builtin_amdgcn_mfma_f32_16x16x32_bf16(af1, bf1, acc11, 0, 0, 0);
        if (wv >= 2) {
            short8 aq = *(const short8*)(qsB + ks * 64 + coff);
            xacc = __builtin_amdgcn_mfma_f32_16x16x32_bf16(aq, (wv == 2) ? bf0 : bf1, xacc, 0, 0, 0);
        }
        __syncthreads();
    }
    #undef STAGE

    // waves 2,3: publish x values (all D rows identical; use reg 0) and x^2 partial
    if (wv >= 2) {
        float xv = xacc[0] + ((wv == 2) ? bv0 : bv1);
        if (l < 16) xvs[(wv - 2) * 16 + l] = xv;
        float px = xv * xv;
        #pragma unroll
        for (int m = 1; m < 16; m <<= 1) px += __shfl_xor(px, m);
        if (l == 0) xred[wv - 2] = px;
    }
    __syncthreads();

    float xv0 = xvs[l & 15];
    float xv1 = xvs[16 + (l & 15)];
    #pragma unroll
    for (int mf = 0; mf < 2; ++mf) {
        f32x4 a0 = mf ? acc10 : acc00;
        f32x4 a1 = mf ? acc11 : acc01;
        #pragma unroll
        for (int reg = 0; reg < 4; ++reg) {
            float y0 = a0[reg] + bv0;
            float y1 = a1[reg] + bv1;
            float y2v = y0 * y0 + y1 * y1;
            float xyv = xv0 * y0 + xv1 * y1;
            #pragma unroll
            for (int m = 1; m < 16; m <<= 1) {
                y2v += __shfl_xor(y2v, m);
                xyv += __shfl_xor(xyv, m);
            }
            if ((l & 15) == 0) {
                int lrow = wv * 32 + mf * 16 + (l >> 4) * 4 + reg;
                red[lrow][0] = y2v;
                red[lrow][1] = xyv;
            }
        }
    }
    __syncthreads();
    if (tid < 128) yn2p[bx * 2048 + rbase + tid] = red[tid][0];
    else           dotp[bx * 2048 + rbase + tid - 128] = red[tid - 128][1];
    if (tid == 0)  xn2p[bx * 16 + by] = xred[0] + xred[1];
}

// ============ kernel 3: finalize + mean (single block, 16 waves, wave = batch) ======
__global__ __launch_bounds__(1024) void final_k(
        const float* __restrict__ yn2p, const float* __restrict__ dotp,
        const float* __restrict__ xn2p,
        const int* __restrict__ labels, const int* __restrict__ events,
        float* __restrict__ out) {
    __shared__ float ln16[16];
    int tid = threadIdx.x;
    int w = tid >> 6, l = tid & 63;   // w = batch

    float xs = (l < 32) ? xn2p[l * 16 + w] : 0.f;
    #pragma unroll
    for (int m = 32; m; m >>= 1) xs += __shfl_xor(xs, m);
    float xn = sqrtf(xs);

    float numt = 0.f, dent = 0.f;
    #pragma unroll
    for (int half = 0; half < 2; ++half) {
        int row = w * 128 + half * 64 + l;
        float y2 = 0.f, dt = 0.f;
        #pragma unroll
        for (int i = 0; i < 32; ++i) {
            y2 += yn2p[i * 2048 + row];
            dt += dotp[i * 2048 + row];
        }
        float yn = sqrtf(y2);
        float c = dt / fmaxf(xn * yn, 1e-8f);
        float e = expf(c);
        numt += e * (float)labels[row];
        dent += e * (float)events[row];
    }
    #pragma unroll
    for (int m = 32; m; m >>= 1) { numt += __shfl_xor(numt, m); dent += __shfl_xor(dent, m); }
    if (l == 0) ln16[w] = logf(dent) - logf(numt);
    __syncthreads();
    if (w == 0) {
        float v = (l < 16) ? ln16[l] : 0.f;
        #pragma unroll
        for (int m = 32; m; m >>= 1) v += __shfl_xor(v, m);
        if (tid == 0) out[0] = v * (1.0f / Bn);
    }
}

extern "C" void kernel_launch(void* const* d_in, const int* in_sizes, int n_in,
                              void* d_out, int out_size, void* d_ws, size_t ws_size,
                              hipStream_t stream) {
    const int*   input_ids = (const int*)d_in[0];
    const float* q         = (const float*)d_in[1];
    const float* seq       = (const float*)d_in[2];
    const int*   events    = (const int*)d_in[3];
    const int*   labels    = (const int*)d_in[4];
    const int*   offsets   = (const int*)d_in[5];
    const float* W         = (const float*)d_in[7];
    const float* bias      = (const float*)d_in[8];
    float* out = (float*)d_out;

    char* ws = (char*)d_ws;
    unsigned short* Apack = (unsigned short*)(ws);                 // 4 MB
    unsigned short* Wb    = (unsigned short*)(ws + 4194304);       // 2 MB
    unsigned short* Qb    = (unsigned short*)(ws + 6291456);       // 32 KB
    float*          yn2p  = (float*)(ws + 6356992);                // 256 KB  [32][2048]
    float*          dotp  = (float*)(ws + 6619136);                // 256 KB  [32][2048]
    float*          xn2p  = (float*)(ws + 6881280);                // 2 KB    [32][16]

    prep_k <<<400, 256, 0, stream>>>(input_ids, q, seq, offsets, W, Apack, Wb, Qb);
    gemm_k <<<512, 256, 0, stream>>>(Apack, Wb, Qb, bias, yn2p, dotp, xn2p);
    final_k<<<1, 1024, 0, stream>>>(yn2p, dotp, xn2p, labels, events, out);
}